// Round 8
// baseline (476.562 us; speedup 1.0000x reference)
//
#include <hip/hip_runtime.h>

#define HID 64
#define NGRAPHS 64
#define LIN_NODES 64

// ---------------- degree count + ticket ----------------
// Plain device-scope atomics (R3: address-spreading null; R4: XCD-scope null ->
// flat ~26G/s memory-side cost per atomic is the floor). In-degree atomic's
// return value = edge's slot within its dst node -> k_fill needs no atomics.
__global__ void k_deg(const int* __restrict__ src, const int* __restrict__ dst,
                      int* __restrict__ dgO, int* __restrict__ dgI,
                      unsigned short* __restrict__ gt, int E) {
  int e = blockIdx.x * 256 + threadIdx.x;
  if (e >= E) return;
  atomicAdd(&dgO[src[e]], 1);
  int t = atomicAdd(&dgI[dst[e]], 1);
  gt[e] = (unsigned short)t;   // in-degree << 65536
}

// ---------------- norms + block-level scan of in-degree (fused) ----------------
__global__ void k_norm_scan(const int* __restrict__ dgO, const int* __restrict__ dgI,
                            float* __restrict__ nO, float* __restrict__ nI,
                            int* __restrict__ excl, int* __restrict__ blksum, int N) {
  __shared__ int s[256];
  int t = threadIdx.x;
  int n = blockIdx.x * 256 + t;
  int di = 0;
  if (n < N) {
    int o = dgO[n];
    di = dgI[n];
    nO[n] = rsqrtf((float)(o > 1 ? o : 1));
    nI[n] = rsqrtf((float)(di > 1 ? di : 1));
  }
  s[t] = di;
  __syncthreads();
  for (int o = 1; o < 256; o <<= 1) {
    int x = (t >= o) ? s[t - o] : 0;
    __syncthreads();
    s[t] += x;
    __syncthreads();
  }
  if (n < N) excl[n] = s[t] - di;          // exclusive within block
  if (t == 255) blksum[blockIdx.x] = s[255];
}

// single-block exclusive scan of up to 4096 block sums (1024 thr x 4 serial)
__global__ void k_scan2(int* __restrict__ blksum, int nb) {
  __shared__ int s[1024];
  int t = threadIdx.x;
  int base = t * 4;
  int v0 = base + 0 < nb ? blksum[base + 0] : 0;
  int v1 = base + 1 < nb ? blksum[base + 1] : 0;
  int v2 = base + 2 < nb ? blksum[base + 2] : 0;
  int v3 = base + 3 < nb ? blksum[base + 3] : 0;
  int sum = v0 + v1 + v2 + v3;
  s[t] = sum;
  __syncthreads();
  for (int o = 1; o < 1024; o <<= 1) {
    int x = (t >= o) ? s[t - o] : 0;
    __syncthreads();
    s[t] += x;
    __syncthreads();
  }
  int excl = s[t] - sum;
  if (base + 0 < nb) blksum[base + 0] = excl;
  if (base + 1 < nb) blksum[base + 1] = excl + v0;
  if (base + 2 < nb) blksum[base + 2] = excl + v0 + v1;
  if (base + 3 < nb) blksum[base + 3] = excl + v0 + v1 + v2;
}

// bucket-fill, NO atomics; block-scan offset folded in (blks[d>>8], 1.6KB L1-hot)
__global__ void k_fill(const int* __restrict__ src, const int* __restrict__ dst,
                       const unsigned short* __restrict__ gt,
                       const int* __restrict__ offs, const int* __restrict__ blks,
                       int* __restrict__ csr, int E) {
  int e = blockIdx.x * 256 + threadIdx.x;
  if (e >= E) return;
  int d = dst[e];
  csr[offs[d] + blks[d >> 8] + gt[e]] = src[e];
}

// ---------------- embedding gather, pre-scaled by norm_out ----------------
__global__ void k_embed(const int* __restrict__ feat, const float* __restrict__ emb,
                        const float* __restrict__ nO, float* __restrict__ h, int N) {
  int t = blockIdx.x * 256 + threadIdx.x;
  int n = t >> 4, q = t & 15;
  if (n >= N) return;
  float4 v = *(const float4*)(emb + (size_t)feat[n] * HID + q * 4);
  float s = nO[n];
  v.x *= s; v.y *= s; v.z *= s; v.w *= s;
  *(float4*)(h + (size_t)n * HID + q * 4) = v;
}

// ---------------- fused gather + linear ----------------
// Per block: 64 nodes. Phase A: 4 lanes/node gather sum(hs[src]) (64B/lane)
// into LDS x-tile scaled by nI. Phase B: 64x64 matmul, relu, opt postscale.
// Reads hs randomly -> must write to a different buffer (ping-pong).
__global__ __launch_bounds__(256) void k_gl(
    const float* __restrict__ hs, const int* __restrict__ csr,
    const int* __restrict__ offs, const int* __restrict__ blks,
    const int* __restrict__ deg, const float* __restrict__ nI,
    const float* __restrict__ W, const float* __restrict__ b,
    float* __restrict__ out, int N, const float* __restrict__ postscale) {
  __shared__ float Ws[HID * HID];        // 16 KB
  __shared__ float xs[LIN_NODES * HID];  // 16 KB
  int t = threadIdx.x;
  for (int i = t * 4; i < HID * HID; i += 256 * 4)
    *(float4*)(Ws + i) = *(const float4*)(W + i);

  int n0 = blockIdx.x * LIN_NODES;
  int gnode = t >> 2, q = t & 3;         // 64 nodes x 4 lanes; lane q = cols q*16..+15
  int n = n0 + gnode;
  float4 a0 = make_float4(0.f, 0.f, 0.f, 0.f), a1 = a0, a2 = a0, a3 = a0;
  if (n < N) {
    int r0 = offs[n] + blks[n >> 8];
    int d = deg[n];
    const float* hq = hs + q * 16;
    int i = 0;
    for (; i + 1 < d; i += 2) {
      int s0 = csr[r0 + i], s1 = csr[r0 + i + 1];
      const float* p0 = hq + (size_t)s0 * HID;
      const float* p1 = hq + (size_t)s1 * HID;
      float4 v0 = *(const float4*)(p0);
      float4 v1 = *(const float4*)(p0 + 4);
      float4 v2 = *(const float4*)(p0 + 8);
      float4 v3 = *(const float4*)(p0 + 12);
      float4 w0 = *(const float4*)(p1);
      float4 w1 = *(const float4*)(p1 + 4);
      float4 w2 = *(const float4*)(p1 + 8);
      float4 w3 = *(const float4*)(p1 + 12);
      a0.x += v0.x + w0.x; a0.y += v0.y + w0.y; a0.z += v0.z + w0.z; a0.w += v0.w + w0.w;
      a1.x += v1.x + w1.x; a1.y += v1.y + w1.y; a1.z += v1.z + w1.z; a1.w += v1.w + w1.w;
      a2.x += v2.x + w2.x; a2.y += v2.y + w2.y; a2.z += v2.z + w2.z; a2.w += v2.w + w2.w;
      a3.x += v3.x + w3.x; a3.y += v3.y + w3.y; a3.z += v3.z + w3.z; a3.w += v3.w + w3.w;
    }
    if (i < d) {
      int s0 = csr[r0 + i];
      const float* p0 = hq + (size_t)s0 * HID;
      float4 v0 = *(const float4*)(p0);
      float4 v1 = *(const float4*)(p0 + 4);
      float4 v2 = *(const float4*)(p0 + 8);
      float4 v3 = *(const float4*)(p0 + 12);
      a0.x += v0.x; a0.y += v0.y; a0.z += v0.z; a0.w += v0.w;
      a1.x += v1.x; a1.y += v1.y; a1.z += v1.z; a1.w += v1.w;
      a2.x += v2.x; a2.y += v2.y; a2.z += v2.z; a2.w += v2.w;
      a3.x += v3.x; a3.y += v3.y; a3.z += v3.z; a3.w += v3.w;
    }
    float sc = nI[n];
    a0.x *= sc; a0.y *= sc; a0.z *= sc; a0.w *= sc;
    a1.x *= sc; a1.y *= sc; a1.z *= sc; a1.w *= sc;
    a2.x *= sc; a2.y *= sc; a2.z *= sc; a2.w *= sc;
    a3.x *= sc; a3.y *= sc; a3.z *= sc; a3.w *= sc;
  }
  float* xp = xs + gnode * HID + q * 16;
  *(float4*)(xp) = a0;
  *(float4*)(xp + 4) = a1;
  *(float4*)(xp + 8) = a2;
  *(float4*)(xp + 12) = a3;
  __syncthreads();

  int j = t & 63, rg = t >> 6;  // 4 waves, each handles 16 nodes; lane j = out col
  float bj = b[j];
  for (int r = 0; r < LIN_NODES / 4; ++r) {
    int node = rg * (LIN_NODES / 4) + r;
    float acc = bj;
#pragma unroll
    for (int k = 0; k < HID; ++k)
      acc = fmaf(xs[node * HID + k], Ws[k * HID + j], acc);
    int nn = n0 + node;
    if (nn < N) {
      float ps = postscale ? postscale[nn] : 1.f;
      out[(size_t)nn * HID + j] = fmaxf(acc, 0.f) * ps;
    }
  }
}

// ---------------- per-graph sum + count (gid sorted -> run-length, wave-uniform) ----
__global__ __launch_bounds__(256) void k_pool(
    const float* __restrict__ h, const int* __restrict__ gid,
    float* __restrict__ sums, int* __restrict__ cnt, int N) {
  int t = threadIdx.x;
  int j = t & 63, sub = t >> 6;
  int base = blockIdx.x * 256 + sub * 64;
  int cur = -1, rl = 0;
  float acc = 0.f;
  for (int i = 0; i < 64; ++i) {
    int n = base + i;
    if (n >= N) break;
    int g = gid[n];
    float v = h[(size_t)n * HID + j];
    if (g != cur) {
      if (cur >= 0) {
        unsafeAtomicAdd(&sums[cur * HID + j], acc);
        if (j == 0) atomicAdd(&cnt[cur], rl);
      }
      cur = g; acc = v; rl = 1;
    } else {
      acc += v; ++rl;
    }
  }
  if (cur >= 0) {
    unsafeAtomicAdd(&sums[cur * HID + j], acc);
    if (j == 0) atomicAdd(&cnt[cur], rl);
  }
}

// ---------------- mean ----------------
__global__ void k_div(const float* __restrict__ sums, const int* __restrict__ cnt,
                      float* __restrict__ out) {
  int i = blockIdx.x * 256 + threadIdx.x;
  if (i >= NGRAPHS * HID) return;
  float c = (float)cnt[i >> 6];
  out[i] = sums[i] / fmaxf(c, 1.f);
}

extern "C" void kernel_launch(void* const* d_in, const int* in_sizes, int n_in,
                              void* d_out, int out_size, void* d_ws, size_t ws_size,
                              hipStream_t stream) {
  const int* node_feat = (const int*)d_in[0];
  const int* src = (const int*)d_in[1];
  const int* dst = (const int*)d_in[2];
  const int* gid = (const int*)d_in[3];
  const float* emb = (const float*)d_in[4];
  const float* W[3] = {(const float*)d_in[5], (const float*)d_in[7], (const float*)d_in[9]};
  const float* b[3] = {(const float*)d_in[6], (const float*)d_in[8], (const float*)d_in[10]};
  float* out = (float*)d_out;
  int N = in_sizes[0];
  int E = in_sizes[1];
  int nblk = (N + 255) / 256;  // 391 for N=100000

  char* ws = (char*)d_ws;
  size_t off_b = 0;
  auto alloc = [&](size_t bytes) {
    char* p = ws + off_b;
    off_b = (off_b + bytes + 255) & ~(size_t)255;
    return p;
  };
  // All zero-init buffers first; ONE memset covers the whole span (padding incl).
  int* dgO = (int*)alloc((size_t)2 * N * 4);   // dgO | dgI contiguous
  int* dgI = dgO + N;
  float* sums = (float*)alloc(NGRAPHS * HID * 4);
  int* cnt = (int*)alloc(NGRAPHS * 4);
  size_t zero_span = off_b;                     // bytes from ws start to zero
  float* nO = (float*)alloc((size_t)N * 4);
  float* nI = (float*)alloc((size_t)N * 4);
  int* offs = (int*)alloc((size_t)N * 4);
  int* blks = (int*)alloc(4096 * 4);
  unsigned short* gt = (unsigned short*)alloc((size_t)E * 2);
  int* csr = (int*)alloc((size_t)E * 4);
  float* h0 = (float*)alloc((size_t)N * HID * 4);
  float* h1 = (float*)alloc((size_t)N * HID * 4);

  hipMemsetAsync(ws, 0, zero_span, stream);

  // degrees + tickets
  k_deg<<<(E + 255) / 256, 256, 0, stream>>>(src, dst, dgO, dgI, gt, E);
  // norms + scan level 1 (fused), then block-sum scan; fill folds blks add
  k_norm_scan<<<nblk, 256, 0, stream>>>(dgO, dgI, nO, nI, offs, blks, N);
  k_scan2<<<1, 1024, 0, stream>>>(blks, nblk);
  k_fill<<<(E + 255) / 256, 256, 0, stream>>>(src, dst, gt, offs, blks, csr, E);

  // h0 = emb[feat] * nO
  k_embed<<<((size_t)N * 16 + 255) / 256, 256, 0, stream>>>(node_feat, emb, nO, h0, N);

  // fused gather+linear, ping-pong h0 <-> h1
  int nblkG = (N + LIN_NODES - 1) / LIN_NODES;
  k_gl<<<nblkG, 256, 0, stream>>>(h0, csr, offs, blks, dgI, nI, W[0], b[0], h1, N, nO);
  k_gl<<<nblkG, 256, 0, stream>>>(h1, csr, offs, blks, dgI, nI, W[1], b[1], h0, N, nO);
  k_gl<<<nblkG, 256, 0, stream>>>(h0, csr, offs, blks, dgI, nI, W[2], b[2], h1, N, nullptr);

  k_pool<<<nblk, 256, 0, stream>>>(h1, gid, sums, cnt, N);
  k_div<<<(NGRAPHS * HID + 255) / 256, 256, 0, stream>>>(sums, cnt, out);
}